// Round 4
// baseline (205.513 us; speedup 1.0000x reference)
//
#include <hip/hip_runtime.h>
#include <cstddef>
#include <cstdint>

typedef __attribute__((ext_vector_type(8))) short bf16x8;   // 8 bf16 = 4 VGPR
typedef __attribute__((ext_vector_type(16))) float f32x16;  // MFMA 32x32 acc

static constexpr int TM = 128;   // edges per block
static constexpr float LN2 = 0.69314718055994530942f;
static constexpr float INV_LN2 = 1.44269504088896340736f;

__device__ __forceinline__ unsigned short f2bf(float f) {
  unsigned int u = __float_as_uint(f);
  u += 0x7fffu + ((u >> 16) & 1u);   // RNE
  return (unsigned short)(u >> 16);
}

// v_cvt_pk_bf16_f32 (gfx950): D[15:0]=bf16(a), D[31:16]=bf16(b), RNE
__device__ __forceinline__ unsigned int cvt_pk_bf16(float a, float b) {
  unsigned int r;
  asm("v_cvt_pk_bf16_f32 %0, %1, %2" : "=v"(r) : "v"(a), "v"(b));
  return r;
}

// HW transcendentals: v_exp_f32 = 2^x, v_log_f32 = log2(x)
__device__ __forceinline__ float hw_exp2(float x) {
  float r;
  asm("v_exp_f32 %0, %1" : "=v"(r) : "v"(x));
  return r;
}
__device__ __forceinline__ float hw_log2(float x) {
  float r;
  asm("v_log_f32 %0, %1" : "=v"(r) : "v"(x));
  return r;
}

// softplus(x)-ln2 = max(x,0)-ln2 + ln2*log2(1+2^(-|x|/ln2)); rel err ~1e-5
__device__ __forceinline__ float shsp(float x) {
  float t = hw_exp2(-fabsf(x) * INV_LN2);
  float l = hw_log2(1.0f + t);
  return fmaf(LN2, l, fmaxf(x, 0.0f) - LN2);
}

// async 16B global -> LDS (lane l writes lptr + l*16; gptr is per-lane)
__device__ __forceinline__ void async_copy16(const void* g, void* l) {
  __builtin_amdgcn_global_load_lds(
      (const __attribute__((address_space(1))) void*)g,
      (__attribute__((address_space(3))) void*)l, 16, 0, 0);
}

// ---- prep: h (N*64 f32) -> bf16 ----
__global__ void prep_h_kernel(const float* __restrict__ h,
                              unsigned short* __restrict__ hbf, int n4) {
  int i = blockIdx.x * 256 + threadIdx.x;
  if (i < n4) {
    float4 v = reinterpret_cast<const float4*>(h)[i];
    uint2 o;
    o.x = cvt_pk_bf16(v.x, v.y);
    o.y = cvt_pk_bf16(v.z, v.w);
    reinterpret_cast<uint2*>(hbf)[i] = o;
  }
}

// ---- prep: pack W1^T, W2^T into MFMA-fragment order (bf16) ----
__global__ void prep_w_kernel(const float* __restrict__ W1,
                              const float* __restrict__ W2,
                              unsigned short* __restrict__ Wp1,
                              unsigned short* __restrict__ Wp2) {
  int j = blockIdx.x * 256 + threadIdx.x;
  if (j < 4 * 12 * 64) {
    int mt = j / (12 * 64);
    int kk = (j / 64) % 12;
    int l  = j % 64;
    int f  = mt * 32 + (l & 31);
    int kb = kk * 16 + (l >> 5) * 8;
    #pragma unroll
    for (int i = 0; i < 8; ++i)
      Wp1[(size_t)j * 8 + i] = f2bf(W1[(size_t)(kb + i) * 128 + f]);
  } else if (j < 4 * 12 * 64 + 2 * 8 * 64) {
    int jj = j - 4 * 12 * 64;
    int mt = jj / (8 * 64);
    int kk = (jj / 64) % 8;
    int l  = jj % 64;
    int oc = mt * 32 + (l & 31);
    int kb = kk * 16 + (l >> 5) * 8;
    #pragma unroll
    for (int i = 0; i < 8; ++i)
      Wp2[(size_t)jj * 8 + i] = f2bf(W2[(size_t)(kb + i) * 64 + oc]);
  }
}

// ---- main fused kernel ----
// LDS 64KB: HA [0,32K) = h1|h2 bf16, 128 rows x 16 chunks x 16B, pos p of
//   row r holds logical chunk p^(r&7) (swizzle moved to GLOBAL source so
//   global_load_lds' linear lane*16 dest works).
// EA [32K,64K) = edge_attr f32, same row/chunk/swizzle scheme (4 f32/chunk);
//   converted to bf16 at fragment-read time. X (hidden, bf16, 256B/row)
//   aliases EA — safe: rows wave-private, program order read-before-write.
__global__ __launch_bounds__(256, 2)
void edge_mlp_kernel(const float* __restrict__ ea,
                     const int* __restrict__ eidx,
                     const float* __restrict__ b1,
                     const float* __restrict__ b2,
                     const unsigned short* __restrict__ hbf,
                     const unsigned short* __restrict__ Wp1,
                     const unsigned short* __restrict__ Wp2,
                     float* __restrict__ out,
                     int E) {
  __shared__ __align__(16) unsigned char LDS[65536];
  unsigned char* HA = LDS;
  unsigned char* EA = LDS + 32768;

  const int tid   = threadIdx.x;
  const int ebase = blockIdx.x * TM;
  const int lane  = tid & 63;
  const int w     = tid >> 6;

  // ---- stage edge_attr (f32, async, no VGPR dest): 8 x 1KB per wave ----
  #pragma unroll
  for (int it = 0; it < 8; ++it) {
    int blk = w * 8 + it;              // 1KB block = 4 rows
    int r   = blk * 4 + (lane >> 4);
    int p   = lane & 15;
    int c   = p ^ (r & 7);             // source chunk for linear dest pos p
    const float* src = ea + (size_t)(ebase + r) * 64 + c * 4;
    async_copy16(src, EA + blk * 1024);
  }
  // ---- stage h[src]|h[dst] gather (async, pre-swizzled source) ----
  #pragma unroll
  for (int it = 0; it < 8; ++it) {
    int blk = w * 8 + it;
    int r   = blk * 4 + (lane >> 4);
    int p   = lane & 15;
    int c   = p ^ (r & 7);             // c<8: h[src] chunk c; c>=8: h[dst]
    int node = eidx[(size_t)(c >> 3) * E + (ebase + r)];
    const unsigned short* src = hbf + (size_t)node * 64 + (c & 7) * 8;
    async_copy16(src, HA + blk * 1024);
  }
  __syncthreads();   // compiler emits vmcnt(0) drain before s_barrier

  const int lo   = lane & 31;
  const int hi   = lane >> 5;
  const int erow = w * 32 + lo;        // wave-private rows [w*32, w*32+32)
  const int rsw  = erow & 7;

  // ---- GEMM1: x^T = W1^T(128x192) @ concat^T, 4 m-tiles of 32 feats ----
  f32x16 acc[4];
  #pragma unroll
  for (int m = 0; m < 4; ++m) acc[m] = (f32x16)0.0f;

  #pragma unroll
  for (int kk = 0; kk < 12; ++kk) {
    bf16x8 bfr;
    if (kk < 8) {      // h part: chunk (kk*2+hi) of HA row
      bfr = *reinterpret_cast<const bf16x8*>(
          HA + erow * 256 + (((kk * 2 + hi) ^ rsw) * 16));
    } else {           // ea part: 8 consecutive f32 -> bf16x8
      int c0 = (kk - 8) * 4 + hi * 2;
      float4 lo4 = *reinterpret_cast<const float4*>(
          EA + erow * 256 + ((c0 ^ rsw) * 16));
      float4 hi4 = *reinterpret_cast<const float4*>(
          EA + erow * 256 + (((c0 + 1) ^ rsw) * 16));
      union { bf16x8 v; unsigned u[4]; } t;
      t.u[0] = cvt_pk_bf16(lo4.x, lo4.y);
      t.u[1] = cvt_pk_bf16(lo4.z, lo4.w);
      t.u[2] = cvt_pk_bf16(hi4.x, hi4.y);
      t.u[3] = cvt_pk_bf16(hi4.z, hi4.w);
      bfr = t.v;
    }
    #pragma unroll
    for (int mt = 0; mt < 4; ++mt) {
      bf16x8 afr = *reinterpret_cast<const bf16x8*>(
          Wp1 + ((size_t)(mt * 12 + kk) * 64 + lane) * 8);
      acc[mt] = __builtin_amdgcn_mfma_f32_32x32x16_bf16(afr, bfr, acc[mt], 0, 0, 0);
    }
  }

  // ---- bias + shifted softplus -> bf16 -> X rows (alias EA, wave-private) ----
  #pragma unroll
  for (int mt = 0; mt < 4; ++mt) {
    #pragma unroll
    for (int g = 0; g < 4; ++g) {
      int f0 = mt * 32 + g * 8 + hi * 4;      // 4 consecutive features
      float4 bb = *reinterpret_cast<const float4*>(b1 + f0);
      float s0 = shsp(acc[mt][g * 4 + 0] + bb.x);
      float s1 = shsp(acc[mt][g * 4 + 1] + bb.y);
      float s2 = shsp(acc[mt][g * 4 + 2] + bb.z);
      float s3 = shsp(acc[mt][g * 4 + 3] + bb.w);
      uint2 o;
      o.x = cvt_pk_bf16(s0, s1);
      o.y = cvt_pk_bf16(s2, s3);
      int chunk = (mt * 4 + g) ^ rsw;
      *reinterpret_cast<uint2*>(EA + erow * 256 + chunk * 16 + hi * 8) = o;
    }
  }
  // no barrier: each wave reads only its own 32 rows

  // ---- GEMM2: out^T = W2^T(64x128) @ x, 2 m-tiles of 32 ocs, K=128 ----
  f32x16 acc2[2];
  #pragma unroll
  for (int m = 0; m < 2; ++m) acc2[m] = (f32x16)0.0f;

  #pragma unroll
  for (int kk = 0; kk < 8; ++kk) {
    bf16x8 bfr = *reinterpret_cast<const bf16x8*>(
        EA + erow * 256 + (((kk * 2 + hi) ^ rsw) * 16));
    #pragma unroll
    for (int mt = 0; mt < 2; ++mt) {
      bf16x8 afr = *reinterpret_cast<const bf16x8*>(
          Wp2 + ((size_t)(mt * 8 + kk) * 64 + lane) * 8);
      acc2[mt] = __builtin_amdgcn_mfma_f32_32x32x16_bf16(afr, bfr, acc2[mt], 0, 0, 0);
    }
  }

  // ---- bias + store: out[e][oc], 16B per store ----
  #pragma unroll
  for (int mt = 0; mt < 2; ++mt) {
    #pragma unroll
    for (int g = 0; g < 4; ++g) {
      int oc0 = mt * 32 + g * 8 + hi * 4;     // 4 consecutive out features
      float4 bb = *reinterpret_cast<const float4*>(b2 + oc0);
      float4 o;
      o.x = acc2[mt][g * 4 + 0] + bb.x;
      o.y = acc2[mt][g * 4 + 1] + bb.y;
      o.z = acc2[mt][g * 4 + 2] + bb.z;
      o.w = acc2[mt][g * 4 + 3] + bb.w;
      *reinterpret_cast<float4*>(out + (size_t)(ebase + erow) * 64 + oc0) = o;
    }
  }
}

extern "C" void kernel_launch(void* const* d_in, const int* in_sizes, int n_in,
                              void* d_out, int out_size, void* d_ws, size_t ws_size,
                              hipStream_t stream) {
  const float* h  = (const float*)d_in[0];
  const float* ea = (const float*)d_in[1];
  const int*  idx = (const int*)d_in[2];
  const float* W1 = (const float*)d_in[3];
  const float* b1 = (const float*)d_in[4];
  const float* W2 = (const float*)d_in[5];
  const float* b2 = (const float*)d_in[6];
  float* out = (float*)d_out;

  const int N = in_sizes[0] / 64;      // 50000
  const int E = in_sizes[1] / 64;      // 800000

  unsigned short* hbf = (unsigned short*)d_ws;                       // N*64 bf16
  size_t off1 = (size_t)N * 64 * 2;
  unsigned short* Wp1 = (unsigned short*)((char*)d_ws + off1);       // 24576 bf16
  unsigned short* Wp2 = (unsigned short*)((char*)d_ws + off1 + 24576 * 2);

  int n4 = (N * 64) / 4;
  prep_h_kernel<<<(n4 + 255) / 256, 256, 0, stream>>>(h, hbf, n4);
  prep_w_kernel<<<16, 256, 0, stream>>>(W1, W2, Wp1, Wp2);

  int nblk = E / TM;                    // 6250
  edge_mlp_kernel<<<nblk, 256, 0, stream>>>(ea, idx, b1, b2, hbf, Wp1, Wp2, out, E);
}